// Round 21
// baseline (162.812 us; speedup 1.0000x reference)
//
#include <hip/hip_runtime.h>
#include <cstdint>
#include <cstddef>

#define N_SEQ 4096
#define D_HEAD 128
#define KP_DIM 256

typedef __attribute__((ext_vector_type(4))) float f32x4;
typedef __attribute__((ext_vector_type(8))) short bf16x8;
typedef __attribute__((ext_vector_type(2))) unsigned int u32x2;

static __device__ __forceinline__ short f2bf(float f) {
  uint32_t u = __builtin_bit_cast(uint32_t, f);
  u += 0x7FFFu + ((u >> 16) & 1u);
  return (short)(u >> 16);
}

static __device__ __forceinline__ float bf2f(short h) {
  return __builtin_bit_cast(float, (uint32_t)((uint16_t)h) << 16);
}

static __device__ __forceinline__ unsigned int cvtpk(float a, float b) {
  unsigned int r;
  asm("v_cvt_pk_bf16_f32 %0, %1, %2" : "=v"(r) : "v"(a), "v"(b));
  return r;
}

static __device__ __forceinline__ int swz8(int r) { return (r ^ (r >> 2)) & 7; }

// ---------------------------------------------------------------------------
// Stage 0: convert E_W,F_W f32 -> bf16 wbf[2][256][4096] (d_out scratch)
// ---------------------------------------------------------------------------
__global__ __launch_bounds__(256) void conv_w_kernel(
    const float* __restrict__ EW, const float* __restrict__ FW,
    short* __restrict__ wbf) {
  const int idx = blockIdx.x * 256 + threadIdx.x;
  const int half = 262144;
  f32x4 v = (idx < half) ? *(const f32x4*)(EW + (size_t)idx * 4)
                         : *(const f32x4*)(FW + (size_t)(idx - half) * 4);
  u32x2 h = {cvtpk(v[0], v[1]), cvtpk(v[2], v[3])};
  *(u32x2*)(wbf + (size_t)idx * 4) = h;
}

// ---------------------------------------------------------------------------
// Stage 1 (v11): partial projections at FULL occupancy. grid 512 = (b,p,s8),
// 1024 thr = 16 waves, __launch_bounds__(1024,8) -> 2 blocks/CU (8 waves/SIMD).
// LDS 64KB/block: W[256][64] SINGLE-buffer (32KB, global_load_lds from
// pre-swizzled bf16 src) + X^T[128][64] x2 (16KB each; depth-2 reg prefetch
// + cvt_pk). 8 iters of BK=64 over this block's 512-n chunk; 2 barriers/iter
// (single-buffer W), stalls covered by the co-resident block.
// XCD owns one s-chunk: W slice 512KB L2-resident; X n-slices L2-shared p0/p1.
// pws[b][p][s 8][k 256][d 128] bf16 partials.
// ---------------------------------------------------------------------------
__global__ __launch_bounds__(1024, 8) void proj_partial_kernel(
    const float* __restrict__ Kin, const float* __restrict__ Vin,
    const short* __restrict__ wbf, short* __restrict__ pws) {
  const int bid = blockIdx.x;                  // 0..511
  const int wk = (bid & 7) * 64 + (bid >> 3);  // XCD x owns wk [64x, 64x+64)
  const int s = wk >> 6;                       // one s-chunk per XCD
  const int p = (wk >> 5) & 1;
  const int b = wk & 31;

  const float* __restrict__ X = (p == 0 ? Kin : Vin) + (size_t)b * (N_SEQ * D_HEAD);
  const short* __restrict__ wp = wbf + (size_t)p * (KP_DIM * N_SEQ);
  short* __restrict__ outp = pws + (((size_t)b * 2 + p) * 8 + s) * (KP_DIM * D_HEAD);

  __shared__ __align__(16) short lw[KP_DIM * 64];     // 32KB: W [256 k][64 n], single
  __shared__ __align__(16) short xt[2][D_HEAD * 64];  // 16KB x2: X^T [128 d][64 n]

  const int t = threadIdx.x;
  const int lane = t & 63;
  const int w = t >> 6;            // 0..15
  const int wkk = (w >> 1) * 32;   // wave k offset (8 groups of 32)
  const int wdd = (w & 1) * 64;    // wave d offset (2 groups of 64)
  const int l15 = lane & 15;
  const int l4 = lane >> 4;
  const int dq = t & 31;           // d-quad for X staging (0..31)
  const int ng = t >> 5;           // n-pair group (0..31) for X staging

  const int n0 = s * 512;          // this block's 512-n chunk

  f32x4 acc[2][4];
#pragma unroll
  for (int i = 0; i < 2; ++i)
#pragma unroll
    for (int j = 0; j < 4; ++j) acc[i][j] = (f32x4){0.f, 0.f, 0.f, 0.f};

  f32x4 xA[2], xB[2];  // depth-2 X prefetch: 2 n-rows per thread

#define PROJ_WISSUE(NC)                                                             \
  do {                                                                              \
    _Pragma("unroll") for (int i_ = 0; i_ < 2; ++i_) {                              \
      int g_ = t + i_ * 1024;                                                       \
      int row_ = g_ >> 3, c_ = g_ & 7;                                              \
      __builtin_amdgcn_global_load_lds(                                             \
          (const __attribute__((address_space(1))) void*)(wp + (size_t)row_ * N_SEQ \
              + (NC) + ((c_ ^ swz8(row_)) << 3)),                                   \
          (__attribute__((address_space(3))) void*)(&lw[g_ * 8]), 16, 0, 0);        \
    }                                                                               \
  } while (0)

#define PROJ_XISSUE(XR, NC)                                                         \
  do {                                                                              \
    _Pragma("unroll") for (int i_ = 0; i_ < 2; ++i_)                                \
      XR[i_] = *(const f32x4*)(X + (size_t)((NC) + ng * 2 + i_) * D_HEAD + dq * 4); \
  } while (0)

#define PROJ_XCVT(XR, BUF)                                                          \
  do {                                                                              \
    _Pragma("unroll") for (int j_ = 0; j_ < 4; ++j_) {                              \
      int drow_ = dq * 4 + j_;                                                      \
      unsigned int hv_ = cvtpk(XR[0][j_], XR[1][j_]);                               \
      *(unsigned int*)(&xt[BUF][drow_ * 64 + ((ng * 2) ^ (swz8(drow_) << 3))]) = hv_; \
    }                                                                               \
  } while (0)

#define PROJ_COMPUTE(CUR)                                                           \
  do {                                                                              \
    _Pragma("unroll") for (int ks2 = 0; ks2 < 2; ++ks2) {                           \
      const int col0 = ks2 * 32 + l4 * 8;                                           \
      bf16x8 a_[2], bb_[4];                                                         \
      _Pragma("unroll") for (int mt_ = 0; mt_ < 2; ++mt_) {                         \
        int row_ = wkk + mt_ * 16 + l15;                                            \
        a_[mt_] = *(const bf16x8*)(&lw[row_ * 64 + (col0 ^ (swz8(row_) << 3))]);    \
      }                                                                             \
      _Pragma("unroll") for (int nt_ = 0; nt_ < 4; ++nt_) {                         \
        int row_ = wdd + nt_ * 16 + l15;                                            \
        bb_[nt_] = *(const bf16x8*)(&xt[CUR][row_ * 64 + (col0 ^ (swz8(row_) << 3))]); \
      }                                                                             \
      _Pragma("unroll") for (int mt_ = 0; mt_ < 2; ++mt_)                           \
        _Pragma("unroll") for (int nt_ = 0; nt_ < 4; ++nt_)                         \
          acc[mt_][nt_] = __builtin_amdgcn_mfma_f32_16x16x32_bf16(a_[mt_], bb_[nt_], \
                                                                  acc[mt_][nt_], 0, 0, 0); \
    }                                                                               \
  } while (0)

  // ---- prologue: W(0) + X(0) staged; X(1) in flight ----
  PROJ_XISSUE(xA, n0);                                   // +2 (X0)
  PROJ_WISSUE(n0);                                       // +2 (W0)
  asm volatile("s_waitcnt vmcnt(2)" ::: "memory");       // X(0) done
  PROJ_XCVT(xA, 0);
  PROJ_XISSUE(xB, n0 + 64);                              // +2 (X1)
  asm volatile("s_waitcnt vmcnt(2)" ::: "memory");       // W(0) done, X(1) flies
  __syncthreads();

  // ---- main: it 0..5 as 3 even/odd pairs; entry invariant X(it+1):2 ----
  for (int itp = 0; itp < 3; ++itp) {
    const int it0 = itp * 2;
    // even iter (cur=0)
    PROJ_COMPUTE(0);
    __syncthreads();                                     // lw free
    PROJ_WISSUE(n0 + (it0 + 1) * 64);                    // +2 -> 4
    PROJ_XISSUE(xA, n0 + (it0 + 2) * 64);                // +2 -> 6
    asm volatile("s_waitcnt vmcnt(4)" ::: "memory");     // X(it+1) done
    PROJ_XCVT(xB, 1);
    asm volatile("s_waitcnt vmcnt(2)" ::: "memory");     // W(it+1) in LDS
    __syncthreads();
    // odd iter (cur=1)
    PROJ_COMPUTE(1);
    __syncthreads();
    PROJ_WISSUE(n0 + (it0 + 2) * 64);
    PROJ_XISSUE(xB, n0 + (it0 + 3) * 64);
    asm volatile("s_waitcnt vmcnt(4)" ::: "memory");
    PROJ_XCVT(xA, 0);
    asm volatile("s_waitcnt vmcnt(2)" ::: "memory");
    __syncthreads();
  }
  // ---- it=6 (cur=0): entry X(7):2 flying; no more X issues ----
  PROJ_COMPUTE(0);
  __syncthreads();
  PROJ_WISSUE(n0 + 7 * 64);                              // +2 -> 4
  asm volatile("s_waitcnt vmcnt(2)" ::: "memory");       // X(7) done
  PROJ_XCVT(xB, 1);
  asm volatile("s_waitcnt vmcnt(0)" ::: "memory");       // W(7) done
  __syncthreads();
  // ---- it=7 (cur=1) ----
  PROJ_COMPUTE(1);

#undef PROJ_WISSUE
#undef PROJ_XISSUE
#undef PROJ_XCVT
#undef PROJ_COMPUTE

  // ---- write bf16 partials ----
#pragma unroll
  for (int mt = 0; mt < 2; ++mt)
#pragma unroll
    for (int nt = 0; nt < 4; ++nt)
#pragma unroll
      for (int r = 0; r < 4; ++r) {
        int kk = wkk + mt * 16 + l4 * 4 + r;
        int dd = wdd + nt * 16 + l15;
        outp[kk * D_HEAD + dd] = f2bf(acc[mt][nt][r]);
      }
}

// ---------------------------------------------------------------------------
// Stage 1b: reduce 8 bf16 partials + bias. grid 256 (8 sub-blocks per b).
// ---------------------------------------------------------------------------
__global__ __launch_bounds__(256) void reduce_bias_kernel(
    const short* __restrict__ pws, const float* __restrict__ Eb,
    const float* __restrict__ Fb, short* __restrict__ kp, short* __restrict__ vpt) {
  const int q = blockIdx.x & 7;
  const int b = blockIdx.x >> 3;
  const int t = threadIdx.x;
  __shared__ short tile[64 * 128];  // 16KB
  if (q < 4) {
    const short* __restrict__ base = pws + ((size_t)b * 16) * 32768;
    const int off = q * 8192;
    for (int i = t; i < 8192; i += 256) {
      int ii = off + i;
      int k = ii >> 7;
      float v = Eb[k];
#pragma unroll
      for (int m = 0; m < 8; ++m) v += bf2f(base[ii + m * 32768]);
      kp[(size_t)b * 32768 + ii] = f2bf(v);
    }
  } else {
    const int kq = q - 4;
    const short* __restrict__ base =
        pws + ((size_t)b * 16 + 8) * 32768 + kq * 64 * D_HEAD;
    for (int i = t; i < 8192; i += 256) {
      int kl = i >> 7, d = i & 127;
      float v = Fb[kq * 64 + kl];
#pragma unroll
      for (int m = 0; m < 8; ++m) v += bf2f(base[i + m * 32768]);
      tile[kl * 128 + (d ^ ((kl & 15) << 3))] = f2bf(v);
    }
    __syncthreads();
    for (int i = t; i < 8192; i += 256) {
      int d = i >> 6, kl = i & 63;
      vpt[(size_t)b * 32768 + d * 256 + kq * 64 + kl] = tile[kl * 128 + (d ^ ((kl & 15) << 3))];
    }
  }
}

// ---------------------------------------------------------------------------
// Stage 2: attention v4 + setprio (verified R18/R20). grid 256, 1024 thr,
// __launch_bounds__(1024,4), 160KB LDS, zero mid-loop barriers.
// ---------------------------------------------------------------------------
__global__ __launch_bounds__(1024, 4) void attn_kernel(
    const float* __restrict__ Q, const short* __restrict__ kp,
    const short* __restrict__ vpt, float* __restrict__ out) {
  const int bid = blockIdx.x;
  const int wk = (bid & 7) * 32 + (bid >> 3);  // XCD-chunked: 4 b's per XCD
  const int b = wk >> 3;
  const int slice = wk & 7;
  const int t = threadIdx.x;
  const int lane = t & 63;
  const int w = t >> 6;  // 0..15
  const int l15 = lane & 15, l4 = lane >> 4;

  __shared__ __align__(16) short lbuf[81920];
  short* lkp = lbuf;
  short* lvpt = lbuf + 32768;
  short* lpw = lbuf + 65536 + w * 1024;  // 2KB/wave

  const short* __restrict__ kpb = kp + (size_t)b * 32768;
  const short* __restrict__ vptb = vpt + (size_t)b * 32768;

#pragma unroll
  for (int i = 0; i < 4; ++i) {
    int g = t + i * 1024;
    int row = g >> 4, c = g & 15;
    __builtin_amdgcn_global_load_lds(
        (const __attribute__((address_space(1))) void*)(kpb + (size_t)row * 128 +
                                                        ((c ^ (row & 7)) << 3)),
        (__attribute__((address_space(3))) void*)(&lkp[g * 8]), 16, 0, 0);
  }
#pragma unroll
  for (int i = 0; i < 4; ++i) {
    int g = t + i * 1024;
    int row = g >> 5, c = g & 31;
    __builtin_amdgcn_global_load_lds(
        (const __attribute__((address_space(1))) void*)(vptb + (size_t)row * 256 +
                                                        ((c ^ (row & 7)) << 3)),
        (__attribute__((address_space(3))) void*)(&lvpt[g * 8]), 16, 0, 0);
  }

  const float scale = 0.08838834764831845f;  // 1/sqrt(128)
  f32x4 qraw[8];
  {
    const float* qr = Q + ((size_t)b * N_SEQ + slice * 512 + w * 16 + l15) * D_HEAD;
#pragma unroll
    for (int ks = 0; ks < 4; ++ks) {
      qraw[2 * ks] = *(const f32x4*)(qr + ks * 32 + l4 * 8);
      qraw[2 * ks + 1] = *(const f32x4*)(qr + ks * 32 + l4 * 8 + 4);
    }
  }
  asm volatile("s_waitcnt vmcnt(0)" ::: "memory");
  __syncthreads();

#pragma unroll
  for (int rd = 0; rd < 2; ++rd) {
    const int rowBase = slice * 512 + rd * 256 + w * 16;

    bf16x8 qf[4];
#pragma unroll
    for (int ks = 0; ks < 4; ++ks) {
      union { unsigned int u[4]; bf16x8 v; } cv;
      cv.u[0] = cvtpk(qraw[2 * ks][0] * scale, qraw[2 * ks][1] * scale);
      cv.u[1] = cvtpk(qraw[2 * ks][2] * scale, qraw[2 * ks][3] * scale);
      cv.u[2] = cvtpk(qraw[2 * ks + 1][0] * scale, qraw[2 * ks + 1][1] * scale);
      cv.u[3] = cvtpk(qraw[2 * ks + 1][2] * scale, qraw[2 * ks + 1][3] * scale);
      qf[ks] = cv.v;
    }

    f32x4 accs[16];
#pragma unroll
    for (int i = 0; i < 16; ++i) accs[i] = (f32x4){0.f, 0.f, 0.f, 0.f};
    __builtin_amdgcn_s_setprio(1);
#pragma unroll
    for (int ks = 0; ks < 4; ++ks) {
#pragma unroll
      for (int nt = 0; nt < 16; ++nt) {
        bf16x8 af = *(const bf16x8*)(&lkp[(nt * 16 + l15) * 128 +
                                          (((ks * 4 + l4) ^ (l15 & 7)) << 3)]);
        accs[nt] = __builtin_amdgcn_mfma_f32_16x16x32_bf16(af, qf[ks], accs[nt], 0, 0, 0);
      }
    }
    __builtin_amdgcn_s_setprio(0);

    float m = -1e30f;
#pragma unroll
    for (int nt = 0; nt < 16; ++nt)
#pragma unroll
      for (int r = 0; r < 4; ++r) m = fmaxf(m, accs[nt][r]);
    m = fmaxf(m, __shfl_xor(m, 16));
    m = fmaxf(m, __shfl_xor(m, 32));
    float s = 0.f;
#pragma unroll
    for (int nt = 0; nt < 16; ++nt)
#pragma unroll
      for (int r = 0; r < 4; ++r) {
        float e = __expf(accs[nt][r] - m);
        accs[nt][r] = e;
        s += e;
      }
    s += __shfl_xor(s, 16);
    s += __shfl_xor(s, 32);
    float inv = 1.0f / s;

    f32x4 acco[8];
#pragma unroll
    for (int i = 0; i < 8; ++i) acco[i] = (f32x4){0.f, 0.f, 0.f, 0.f};
#pragma unroll
    for (int qq = 0; qq < 4; ++qq) {
#pragma unroll
      for (int ntl = 0; ntl < 4; ++ntl) {
        int nt = qq * 4 + ntl;
        int cw = 2 * ntl + (l4 >> 1);
        unsigned int p0 = cvtpk(accs[nt][0] * inv, accs[nt][1] * inv);
        unsigned int p1 = cvtpk(accs[nt][2] * inv, accs[nt][3] * inv);
        *(u32x2*)((char*)lpw + l15 * 128 + ((cw ^ (l15 & 7)) << 4) + (l4 & 1) * 8) =
            (u32x2){p0, p1};
      }
      if (rd == 0 && qq == 3) {
        const float* qr = Q + ((size_t)b * N_SEQ + slice * 512 + 256 + w * 16 + l15) * D_HEAD;
#pragma unroll
        for (int ks = 0; ks < 4; ++ks) {
          qraw[2 * ks] = *(const f32x4*)(qr + ks * 32 + l4 * 8);
          qraw[2 * ks + 1] = *(const f32x4*)(qr + ks * 32 + l4 * 8 + 4);
        }
      }
      __builtin_amdgcn_s_setprio(1);
#pragma unroll
      for (int ksl = 0; ksl < 2; ++ksl) {
        bf16x8 pa = *(const bf16x8*)((char*)lpw + l15 * 128 +
                                     (((4 * ksl + l4) ^ (l15 & 7)) << 4));
        int ksa = qq * 2 + ksl;
#pragma unroll
        for (int ntv = 0; ntv < 8; ++ntv) {
          bf16x8 av = *(const bf16x8*)(&lvpt[(ntv * 16 + l15) * 256 +
                                             (((ksa * 4 + l4) ^ (l15 & 7)) << 3)]);
          acco[ntv] = __builtin_amdgcn_mfma_f32_16x16x32_bf16(av, pa, acco[ntv], 0, 0, 0);
        }
      }
      __builtin_amdgcn_s_setprio(0);
    }

    float* ob = out + ((size_t)b * N_SEQ + rowBase) * D_HEAD;
#pragma unroll
    for (int ntv = 0; ntv < 8; ++ntv)
      *(f32x4*)(ob + (size_t)l15 * D_HEAD + ntv * 16 + l4 * 4) = acco[ntv];
  }
}

// ---------------------------------------------------------------------------
extern "C" void kernel_launch(void* const* d_in, const int* in_sizes, int n_in,
                              void* d_out, int out_size, void* d_ws, size_t ws_size,
                              hipStream_t stream) {
  const float* Q  = (const float*)d_in[0];
  const float* K  = (const float*)d_in[1];
  const float* V  = (const float*)d_in[2];
  const float* EW = (const float*)d_in[3];
  const float* Eb = (const float*)d_in[4];
  const float* FW = (const float*)d_in[5];
  const float* Fb = (const float*)d_in[6];
  float* out = (float*)d_out;

  // d_out scratch (dead before attn writes): [0,4MB) wbf; [8MB,41.5MB) pws bf16
  short* wbf = (short*)d_out;
  short* pws = (short*)((char*)d_out + 8 * 1024 * 1024);
  short* kpb = (short*)d_ws;
  short* vpt = (short*)((char*)d_ws + (size_t)32 * KP_DIM * D_HEAD * 2);

  conv_w_kernel<<<dim3(2048), dim3(256), 0, stream>>>(EW, FW, wbf);
  proj_partial_kernel<<<dim3(512), dim3(1024), 0, stream>>>(K, V, wbf, pws);
  reduce_bias_kernel<<<dim3(256), dim3(256), 0, stream>>>(pws, Eb, Fb, kpb, vpt);
  attn_kernel<<<dim3(256), dim3(1024), 0, stream>>>(Q, kpb, vpt, out);
}

// Round 22
// 85.831 us; speedup vs baseline: 1.8969x; 1.8969x over previous
//
#include <hip/hip_runtime.h>
#include <cstdint>
#include <cstddef>

#define N_SEQ 4096
#define D_HEAD 128
#define KP_DIM 256

typedef __attribute__((ext_vector_type(4))) float f32x4;
typedef __attribute__((ext_vector_type(8))) short bf16x8;
typedef __attribute__((ext_vector_type(2))) unsigned int u32x2;

static __device__ __forceinline__ short f2bf(float f) {
  uint32_t u = __builtin_bit_cast(uint32_t, f);
  u += 0x7FFFu + ((u >> 16) & 1u);
  return (short)(u >> 16);
}

static __device__ __forceinline__ float bf2f(short h) {
  return __builtin_bit_cast(float, (uint32_t)((uint16_t)h) << 16);
}

static __device__ __forceinline__ unsigned int cvtpk(float a, float b) {
  unsigned int r;
  asm("v_cvt_pk_bf16_f32 %0, %1, %2" : "=v"(r) : "v"(a), "v"(b));
  return r;
}

static __device__ __forceinline__ int swz8(int r) { return (r ^ (r >> 2)) & 7; }

// ---------------------------------------------------------------------------
// Stage 0: convert E_W,F_W f32 -> bf16 wbf[2][256][4096] (d_out scratch)
// ---------------------------------------------------------------------------
__global__ __launch_bounds__(256) void conv_w_kernel(
    const float* __restrict__ EW, const float* __restrict__ FW,
    short* __restrict__ wbf) {
  const int idx = blockIdx.x * 256 + threadIdx.x;
  const int half = 262144;
  f32x4 v = (idx < half) ? *(const f32x4*)(EW + (size_t)idx * 4)
                         : *(const f32x4*)(FW + (size_t)(idx - half) * 4);
  u32x2 h = {cvtpk(v[0], v[1]), cvtpk(v[2], v[3])};
  *(u32x2*)(wbf + (size_t)idx * 4) = h;
}

// ---------------------------------------------------------------------------
// Stage 1 (v7.2, R20 best): partial projections, bf16 partials. grid 256
// (1 block/CU, XCD-chunked), 1024 thr = 16 waves (8k x 2d of 32x64).
// Block = (b,p,s): full 256k x 128d over n-chunk s*1024 (16 iters BK=64).
// XCVT hoisted before compute; counted vmcnt, never 0 mid-loop.
// NOTE (R21 lesson): do NOT raise min-waves past 4 — the 64-VGPR cap at
// 8 waves/SIMD spills the ~58-reg live set (127 us, 400 MB scratch traffic).
// ---------------------------------------------------------------------------
__global__ __launch_bounds__(1024, 4) void proj_partial_kernel(
    const float* __restrict__ Kin, const float* __restrict__ Vin,
    const short* __restrict__ wbf, short* __restrict__ pws) {
  const int bid = blockIdx.x;                  // 0..255
  const int wk = (bid & 7) * 32 + (bid >> 3);  // XCD x owns wk [32x, 32x+32)
  const int b = wk & 31;
  const int s = (wk >> 5) & 3;
  const int p = wk >> 7;

  const float* __restrict__ X = (p == 0 ? Kin : Vin) + (size_t)b * (N_SEQ * D_HEAD);
  const short* __restrict__ wp = wbf + (size_t)p * (KP_DIM * N_SEQ);
  short* __restrict__ outp = pws + ((((size_t)b * 2 + p) * 4) + s) * (KP_DIM * D_HEAD);

  __shared__ __align__(16) short lw[2][KP_DIM * 64];  // 32KB x2: W [256 k][64 n]
  __shared__ __align__(16) short xt[2][D_HEAD * 64];  // 16KB x2: X^T [128 d][64 n]

  const int t = threadIdx.x;
  const int lane = t & 63;
  const int w = t >> 6;            // 0..15
  const int wkk = (w >> 1) * 32;   // wave k offset (8 groups of 32)
  const int wdd = (w & 1) * 64;    // wave d offset (2 groups of 64)
  const int l15 = lane & 15;
  const int l4 = lane >> 4;
  const int dq = t & 31;           // d-quad for X staging (0..31)
  const int ng = t >> 5;           // n-pair group (0..31) for X staging

  const int n0 = s * 1024;

  f32x4 acc[2][4];
#pragma unroll
  for (int i = 0; i < 2; ++i)
#pragma unroll
    for (int j = 0; j < 4; ++j) acc[i][j] = (f32x4){0.f, 0.f, 0.f, 0.f};

  f32x4 xA[2], xB[2];  // depth-2 X prefetch: 2 n-rows per thread

#define PROJ_WISSUE(BUF, NC)                                                        \
  do {                                                                              \
    _Pragma("unroll") for (int i_ = 0; i_ < 2; ++i_) {                              \
      int g_ = t + i_ * 1024;                                                       \
      int row_ = g_ >> 3, c_ = g_ & 7;                                              \
      __builtin_amdgcn_global_load_lds(                                             \
          (const __attribute__((address_space(1))) void*)(wp + (size_t)row_ * N_SEQ \
              + (NC) + ((c_ ^ swz8(row_)) << 3)),                                   \
          (__attribute__((address_space(3))) void*)(&lw[BUF][g_ * 8]), 16, 0, 0);   \
    }                                                                               \
  } while (0)

#define PROJ_XISSUE(XR, NC)                                                         \
  do {                                                                              \
    _Pragma("unroll") for (int i_ = 0; i_ < 2; ++i_)                                \
      XR[i_] = *(const f32x4*)(X + (size_t)((NC) + ng * 2 + i_) * D_HEAD + dq * 4); \
  } while (0)

#define PROJ_XCVT(XR, BUF)                                                          \
  do {                                                                              \
    _Pragma("unroll") for (int j_ = 0; j_ < 4; ++j_) {                              \
      int drow_ = dq * 4 + j_;                                                      \
      unsigned int hv_ = cvtpk(XR[0][j_], XR[1][j_]);                               \
      *(unsigned int*)(&xt[BUF][drow_ * 64 + ((ng * 2) ^ (swz8(drow_) << 3))]) = hv_; \
    }                                                                               \
  } while (0)

#define PROJ_COMPUTE(CUR)                                                           \
  do {                                                                              \
    _Pragma("unroll") for (int ks2 = 0; ks2 < 2; ++ks2) {                           \
      const int col0 = ks2 * 32 + l4 * 8;                                           \
      bf16x8 a_[2], bb_[4];                                                         \
      _Pragma("unroll") for (int mt_ = 0; mt_ < 2; ++mt_) {                         \
        int row_ = wkk + mt_ * 16 + l15;                                            \
        a_[mt_] = *(const bf16x8*)(&lw[CUR][row_ * 64 + (col0 ^ (swz8(row_) << 3))]); \
      }                                                                             \
      _Pragma("unroll") for (int nt_ = 0; nt_ < 4; ++nt_) {                         \
        int row_ = wdd + nt_ * 16 + l15;                                            \
        bb_[nt_] = *(const bf16x8*)(&xt[CUR][row_ * 64 + (col0 ^ (swz8(row_) << 3))]); \
      }                                                                             \
      _Pragma("unroll") for (int mt_ = 0; mt_ < 2; ++mt_)                           \
        _Pragma("unroll") for (int nt_ = 0; nt_ < 4; ++nt_)                         \
          acc[mt_][nt_] = __builtin_amdgcn_mfma_f32_16x16x32_bf16(a_[mt_], bb_[nt_], \
                                                                  acc[mt_][nt_], 0, 0, 0); \
    }                                                                               \
  } while (0)

  // ---- prologue ----
  PROJ_XISSUE(xA, n0);                                   // X(0): +2
  PROJ_WISSUE(0, n0);                                    // W(0): +2
  asm volatile("s_waitcnt vmcnt(2)" ::: "memory");       // X(0) done
  PROJ_XCVT(xA, 0);
  PROJ_XISSUE(xB, n0 + 64);                              // X(1): +2
  asm volatile("s_waitcnt vmcnt(2)" ::: "memory");       // W(0) done, X(1) flies
  __syncthreads();

  // ---- main loop: iters 0..13 as 7 even/odd pairs (XCVT-early schedule) ----
  for (int itp = 0; itp < 7; ++itp) {
    const int it0 = itp * 2;
    // even iter (cur=0): entry outstanding = X(it+1):2
    PROJ_WISSUE(1, n0 + (it0 + 1) * 64);                 // W(it+1): +2 -> 4
    PROJ_XISSUE(xA, n0 + (it0 + 2) * 64);                // X(it+2): +2 -> 6
    asm volatile("s_waitcnt vmcnt(4)" ::: "memory");     // X(it+1) done (instant)
    PROJ_XCVT(xB, 1);                                    // fill xt[1] for next iter
    PROJ_COMPUTE(0);
    asm volatile("s_waitcnt vmcnt(2)" ::: "memory");     // W(it+1) done (covered)
    __syncthreads();
    // odd iter (cur=1)
    PROJ_WISSUE(0, n0 + (it0 + 2) * 64);
    PROJ_XISSUE(xB, n0 + (it0 + 3) * 64);
    asm volatile("s_waitcnt vmcnt(4)" ::: "memory");
    PROJ_XCVT(xA, 0);
    PROJ_COMPUTE(1);
    asm volatile("s_waitcnt vmcnt(2)" ::: "memory");
    __syncthreads();
  }
  // ---- it=14 (cur=0): entry outstanding = X(15):2 ----
  PROJ_WISSUE(1, n0 + 15 * 64);                          // W(15): +2 -> 4
  asm volatile("s_waitcnt vmcnt(2)" ::: "memory");       // X(15) done
  PROJ_XCVT(xB, 1);
  PROJ_COMPUTE(0);
  asm volatile("s_waitcnt vmcnt(0)" ::: "memory");       // W(15) done
  __syncthreads();
  // ---- it=15 (cur=1) ----
  PROJ_COMPUTE(1);

#undef PROJ_WISSUE
#undef PROJ_XISSUE
#undef PROJ_XCVT
#undef PROJ_COMPUTE

  // ---- write bf16 partials ----
#pragma unroll
  for (int mt = 0; mt < 2; ++mt)
#pragma unroll
    for (int nt = 0; nt < 4; ++nt)
#pragma unroll
      for (int r = 0; r < 4; ++r) {
        int kk = wkk + mt * 16 + l4 * 4 + r;
        int dd = wdd + nt * 16 + l15;
        outp[kk * D_HEAD + dd] = f2bf(acc[mt][nt][r]);
      }
}

// ---------------------------------------------------------------------------
// Stage 1b: reduce 4 bf16 partials + bias. grid 256 (8 sub-blocks per b).
// ---------------------------------------------------------------------------
__global__ __launch_bounds__(256) void reduce_bias_kernel(
    const short* __restrict__ pws, const float* __restrict__ Eb,
    const float* __restrict__ Fb, short* __restrict__ kp, short* __restrict__ vpt) {
  const int q = blockIdx.x & 7;
  const int b = blockIdx.x >> 3;
  const int t = threadIdx.x;
  __shared__ short tile[64 * 128];  // 16KB
  if (q < 4) {
    const short* __restrict__ base = pws + ((size_t)b * 2) * 4 * 32768;
    const int off = q * 8192;
    for (int i = t; i < 8192; i += 256) {
      int ii = off + i;
      int k = ii >> 7;
      float v = bf2f(base[ii]) + bf2f(base[ii + 32768]) + bf2f(base[ii + 65536]) +
                bf2f(base[ii + 98304]) + Eb[k];
      kp[(size_t)b * 32768 + ii] = f2bf(v);
    }
  } else {
    const int kq = q - 4;
    const short* __restrict__ base =
        pws + (((size_t)b * 2 + 1) * 4) * 32768 + kq * 64 * D_HEAD;
    for (int i = t; i < 8192; i += 256) {
      int kl = i >> 7, d = i & 127;
      float v = bf2f(base[i]) + bf2f(base[i + 32768]) + bf2f(base[i + 65536]) +
                bf2f(base[i + 98304]) + Fb[kq * 64 + kl];
      tile[kl * 128 + (d ^ ((kl & 15) << 3))] = f2bf(v);
    }
    __syncthreads();
    for (int i = t; i < 8192; i += 256) {
      int d = i >> 6, kl = i & 63;
      vpt[(size_t)b * 32768 + d * 256 + kq * 64 + kl] = tile[kl * 128 + (d ^ ((kl & 15) << 3))];
    }
  }
}

// ---------------------------------------------------------------------------
// Stage 2: attention v4 + setprio (verified R18/R20). grid 256, 1024 thr,
// __launch_bounds__(1024,4), 160KB LDS, zero mid-loop barriers.
// ---------------------------------------------------------------------------
__global__ __launch_bounds__(1024, 4) void attn_kernel(
    const float* __restrict__ Q, const short* __restrict__ kp,
    const short* __restrict__ vpt, float* __restrict__ out) {
  const int bid = blockIdx.x;
  const int wk = (bid & 7) * 32 + (bid >> 3);  // XCD-chunked: 4 b's per XCD
  const int b = wk >> 3;
  const int slice = wk & 7;
  const int t = threadIdx.x;
  const int lane = t & 63;
  const int w = t >> 6;  // 0..15
  const int l15 = lane & 15, l4 = lane >> 4;

  __shared__ __align__(16) short lbuf[81920];
  short* lkp = lbuf;
  short* lvpt = lbuf + 32768;
  short* lpw = lbuf + 65536 + w * 1024;  // 2KB/wave

  const short* __restrict__ kpb = kp + (size_t)b * 32768;
  const short* __restrict__ vptb = vpt + (size_t)b * 32768;

#pragma unroll
  for (int i = 0; i < 4; ++i) {
    int g = t + i * 1024;
    int row = g >> 4, c = g & 15;
    __builtin_amdgcn_global_load_lds(
        (const __attribute__((address_space(1))) void*)(kpb + (size_t)row * 128 +
                                                        ((c ^ (row & 7)) << 3)),
        (__attribute__((address_space(3))) void*)(&lkp[g * 8]), 16, 0, 0);
  }
#pragma unroll
  for (int i = 0; i < 4; ++i) {
    int g = t + i * 1024;
    int row = g >> 5, c = g & 31;
    __builtin_amdgcn_global_load_lds(
        (const __attribute__((address_space(1))) void*)(vptb + (size_t)row * 256 +
                                                        ((c ^ (row & 7)) << 3)),
        (__attribute__((address_space(3))) void*)(&lvpt[g * 8]), 16, 0, 0);
  }

  const float scale = 0.08838834764831845f;  // 1/sqrt(128)
  f32x4 qraw[8];
  {
    const float* qr = Q + ((size_t)b * N_SEQ + slice * 512 + w * 16 + l15) * D_HEAD;
#pragma unroll
    for (int ks = 0; ks < 4; ++ks) {
      qraw[2 * ks] = *(const f32x4*)(qr + ks * 32 + l4 * 8);
      qraw[2 * ks + 1] = *(const f32x4*)(qr + ks * 32 + l4 * 8 + 4);
    }
  }
  asm volatile("s_waitcnt vmcnt(0)" ::: "memory");
  __syncthreads();

#pragma unroll
  for (int rd = 0; rd < 2; ++rd) {
    const int rowBase = slice * 512 + rd * 256 + w * 16;

    bf16x8 qf[4];
#pragma unroll
    for (int ks = 0; ks < 4; ++ks) {
      union { unsigned int u[4]; bf16x8 v; } cv;
      cv.u[0] = cvtpk(qraw[2 * ks][0] * scale, qraw[2 * ks][1] * scale);
      cv.u[1] = cvtpk(qraw[2 * ks][2] * scale, qraw[2 * ks][3] * scale);
      cv.u[2] = cvtpk(qraw[2 * ks + 1][0] * scale, qraw[2 * ks + 1][1] * scale);
      cv.u[3] = cvtpk(qraw[2 * ks + 1][2] * scale, qraw[2 * ks + 1][3] * scale);
      qf[ks] = cv.v;
    }

    f32x4 accs[16];
#pragma unroll
    for (int i = 0; i < 16; ++i) accs[i] = (f32x4){0.f, 0.f, 0.f, 0.f};
    __builtin_amdgcn_s_setprio(1);
#pragma unroll
    for (int ks = 0; ks < 4; ++ks) {
#pragma unroll
      for (int nt = 0; nt < 16; ++nt) {
        bf16x8 af = *(const bf16x8*)(&lkp[(nt * 16 + l15) * 128 +
                                          (((ks * 4 + l4) ^ (l15 & 7)) << 3)]);
        accs[nt] = __builtin_amdgcn_mfma_f32_16x16x32_bf16(af, qf[ks], accs[nt], 0, 0, 0);
      }
    }
    __builtin_amdgcn_s_setprio(0);

    float m = -1e30f;
#pragma unroll
    for (int nt = 0; nt < 16; ++nt)
#pragma unroll
      for (int r = 0; r < 4; ++r) m = fmaxf(m, accs[nt][r]);
    m = fmaxf(m, __shfl_xor(m, 16));
    m = fmaxf(m, __shfl_xor(m, 32));
    float s = 0.f;
#pragma unroll
    for (int nt = 0; nt < 16; ++nt)
#pragma unroll
      for (int r = 0; r < 4; ++r) {
        float e = __expf(accs[nt][r] - m);
        accs[nt][r] = e;
        s += e;
      }
    s += __shfl_xor(s, 16);
    s += __shfl_xor(s, 32);
    float inv = 1.0f / s;

    f32x4 acco[8];
#pragma unroll
    for (int i = 0; i < 8; ++i) acco[i] = (f32x4){0.f, 0.f, 0.f, 0.f};
#pragma unroll
    for (int qq = 0; qq < 4; ++qq) {
#pragma unroll
      for (int ntl = 0; ntl < 4; ++ntl) {
        int nt = qq * 4 + ntl;
        int cw = 2 * ntl + (l4 >> 1);
        unsigned int p0 = cvtpk(accs[nt][0] * inv, accs[nt][1] * inv);
        unsigned int p1 = cvtpk(accs[nt][2] * inv, accs[nt][3] * inv);
        *(u32x2*)((char*)lpw + l15 * 128 + ((cw ^ (l15 & 7)) << 4) + (l4 & 1) * 8) =
            (u32x2){p0, p1};
      }
      if (rd == 0 && qq == 3) {
        const float* qr = Q + ((size_t)b * N_SEQ + slice * 512 + 256 + w * 16 + l15) * D_HEAD;
#pragma unroll
        for (int ks = 0; ks < 4; ++ks) {
          qraw[2 * ks] = *(const f32x4*)(qr + ks * 32 + l4 * 8);
          qraw[2 * ks + 1] = *(const f32x4*)(qr + ks * 32 + l4 * 8 + 4);
        }
      }
      __builtin_amdgcn_s_setprio(1);
#pragma unroll
      for (int ksl = 0; ksl < 2; ++ksl) {
        bf16x8 pa = *(const bf16x8*)((char*)lpw + l15 * 128 +
                                     (((4 * ksl + l4) ^ (l15 & 7)) << 4));
        int ksa = qq * 2 + ksl;
#pragma unroll
        for (int ntv = 0; ntv < 8; ++ntv) {
          bf16x8 av = *(const bf16x8*)(&lvpt[(ntv * 16 + l15) * 256 +
                                             (((ksa * 4 + l4) ^ (l15 & 7)) << 3)]);
          acco[ntv] = __builtin_amdgcn_mfma_f32_16x16x32_bf16(av, pa, acco[ntv], 0, 0, 0);
        }
      }
      __builtin_amdgcn_s_setprio(0);
    }

    float* ob = out + ((size_t)b * N_SEQ + rowBase) * D_HEAD;
#pragma unroll
    for (int ntv = 0; ntv < 8; ++ntv)
      *(f32x4*)(ob + (size_t)l15 * D_HEAD + ntv * 16 + l4 * 4) = acco[ntv];
  }
}

// ---------------------------------------------------------------------------
extern "C" void kernel_launch(void* const* d_in, const int* in_sizes, int n_in,
                              void* d_out, int out_size, void* d_ws, size_t ws_size,
                              hipStream_t stream) {
  const float* Q  = (const float*)d_in[0];
  const float* K  = (const float*)d_in[1];
  const float* V  = (const float*)d_in[2];
  const float* EW = (const float*)d_in[3];
  const float* Eb = (const float*)d_in[4];
  const float* FW = (const float*)d_in[5];
  const float* Fb = (const float*)d_in[6];
  float* out = (float*)d_out;

  // d_out scratch (dead before attn writes): [0,4MB) wbf; [8MB,24.8MB) pws bf16
  short* wbf = (short*)d_out;
  short* pws = (short*)((char*)d_out + 8 * 1024 * 1024);
  short* kpb = (short*)d_ws;
  short* vpt = (short*)((char*)d_ws + (size_t)32 * KP_DIM * D_HEAD * 2);

  conv_w_kernel<<<dim3(2048), dim3(256), 0, stream>>>(EW, FW, wbf);
  proj_partial_kernel<<<dim3(256), dim3(1024), 0, stream>>>(K, V, wbf, pws);
  reduce_bias_kernel<<<dim3(256), dim3(256), 0, stream>>>(pws, Eb, Fb, kpb, vpt);
  attn_kernel<<<dim3(256), dim3(1024), 0, stream>>>(Q, kpb, vpt, out);
}

// Round 23
// 85.695 us; speedup vs baseline: 1.8999x; 1.0016x over previous
//
#include <hip/hip_runtime.h>
#include <cstdint>
#include <cstddef>

#define N_SEQ 4096
#define D_HEAD 128
#define KP_DIM 256

// ===========================================================================
// FINAL CONFIGURATION (plateau, verified 85.8-86.1 us across R20/R22):
//   conv_w (~2us) -> proj_partial v7.2 (~57us) -> reduce_bias (~3us)
//   -> attn v4+setprio (~24us, at HBM floor).
// proj is latency/sync-bound (2-phase structure stall per m233), NOT
// pipe-bound; 7 structural rewrites (v5-v11) all landed 57-67us or worse.
// Known dead ends: 8 waves/SIMD (VGPR-64 cap spills, R21: 127us);
// fused atomic-tail reduce (LDS>80KB -> 1 blk/CU + L2 eviction, R16: 267us);
// W-direct-from-L2 (per-MFMA L2 latency, R11/R14).
// ===========================================================================

typedef __attribute__((ext_vector_type(4))) float f32x4;
typedef __attribute__((ext_vector_type(8))) short bf16x8;
typedef __attribute__((ext_vector_type(2))) unsigned int u32x2;

static __device__ __forceinline__ short f2bf(float f) {
  uint32_t u = __builtin_bit_cast(uint32_t, f);
  u += 0x7FFFu + ((u >> 16) & 1u);
  return (short)(u >> 16);
}

static __device__ __forceinline__ float bf2f(short h) {
  return __builtin_bit_cast(float, (uint32_t)((uint16_t)h) << 16);
}

static __device__ __forceinline__ unsigned int cvtpk(float a, float b) {
  unsigned int r;
  asm("v_cvt_pk_bf16_f32 %0, %1, %2" : "=v"(r) : "v"(a), "v"(b));
  return r;
}

static __device__ __forceinline__ int swz8(int r) { return (r ^ (r >> 2)) & 7; }

// ---------------------------------------------------------------------------
// Stage 0: convert E_W,F_W f32 -> bf16 wbf[2][256][4096] (d_out scratch)
// ---------------------------------------------------------------------------
__global__ __launch_bounds__(256) void conv_w_kernel(
    const float* __restrict__ EW, const float* __restrict__ FW,
    short* __restrict__ wbf) {
  const int idx = blockIdx.x * 256 + threadIdx.x;
  const int half = 262144;
  f32x4 v = (idx < half) ? *(const f32x4*)(EW + (size_t)idx * 4)
                         : *(const f32x4*)(FW + (size_t)(idx - half) * 4);
  u32x2 h = {cvtpk(v[0], v[1]), cvtpk(v[2], v[3])};
  *(u32x2*)(wbf + (size_t)idx * 4) = h;
}

// ---------------------------------------------------------------------------
// Stage 1 (v7.2 final): partial projections, bf16 partials. grid 256
// (1 block/CU, XCD-chunked), 1024 thr = 16 waves (8k x 2d of 32x64).
// Block = (b,p,s): full 256k x 128d over n-chunk s*1024 (16 iters BK=64).
// W via global_load_lds from pre-converted bf16 (pre-swizzled source);
// X depth-2 reg prefetch + cvt_pk, XCVT hoisted before compute (X-wait
// instant at iter entry, W-wait covered by compute); counted vmcnt,
// never 0 mid-loop. Do NOT raise min-waves past 4 (R21: spill).
// ---------------------------------------------------------------------------
__global__ __launch_bounds__(1024, 4) void proj_partial_kernel(
    const float* __restrict__ Kin, const float* __restrict__ Vin,
    const short* __restrict__ wbf, short* __restrict__ pws) {
  const int bid = blockIdx.x;                  // 0..255
  const int wk = (bid & 7) * 32 + (bid >> 3);  // XCD x owns wk [32x, 32x+32)
  const int b = wk & 31;
  const int s = (wk >> 5) & 3;
  const int p = wk >> 7;

  const float* __restrict__ X = (p == 0 ? Kin : Vin) + (size_t)b * (N_SEQ * D_HEAD);
  const short* __restrict__ wp = wbf + (size_t)p * (KP_DIM * N_SEQ);
  short* __restrict__ outp = pws + ((((size_t)b * 2 + p) * 4) + s) * (KP_DIM * D_HEAD);

  __shared__ __align__(16) short lw[2][KP_DIM * 64];  // 32KB x2: W [256 k][64 n]
  __shared__ __align__(16) short xt[2][D_HEAD * 64];  // 16KB x2: X^T [128 d][64 n]

  const int t = threadIdx.x;
  const int lane = t & 63;
  const int w = t >> 6;            // 0..15
  const int wkk = (w >> 1) * 32;   // wave k offset (8 groups of 32)
  const int wdd = (w & 1) * 64;    // wave d offset (2 groups of 64)
  const int l15 = lane & 15;
  const int l4 = lane >> 4;
  const int dq = t & 31;           // d-quad for X staging (0..31)
  const int ng = t >> 5;           // n-pair group (0..31) for X staging

  const int n0 = s * 1024;

  f32x4 acc[2][4];
#pragma unroll
  for (int i = 0; i < 2; ++i)
#pragma unroll
    for (int j = 0; j < 4; ++j) acc[i][j] = (f32x4){0.f, 0.f, 0.f, 0.f};

  f32x4 xA[2], xB[2];  // depth-2 X prefetch: 2 n-rows per thread

#define PROJ_WISSUE(BUF, NC)                                                        \
  do {                                                                              \
    _Pragma("unroll") for (int i_ = 0; i_ < 2; ++i_) {                              \
      int g_ = t + i_ * 1024;                                                       \
      int row_ = g_ >> 3, c_ = g_ & 7;                                              \
      __builtin_amdgcn_global_load_lds(                                             \
          (const __attribute__((address_space(1))) void*)(wp + (size_t)row_ * N_SEQ \
              + (NC) + ((c_ ^ swz8(row_)) << 3)),                                   \
          (__attribute__((address_space(3))) void*)(&lw[BUF][g_ * 8]), 16, 0, 0);   \
    }                                                                               \
  } while (0)

#define PROJ_XISSUE(XR, NC)                                                         \
  do {                                                                              \
    _Pragma("unroll") for (int i_ = 0; i_ < 2; ++i_)                                \
      XR[i_] = *(const f32x4*)(X + (size_t)((NC) + ng * 2 + i_) * D_HEAD + dq * 4); \
  } while (0)

#define PROJ_XCVT(XR, BUF)                                                          \
  do {                                                                              \
    _Pragma("unroll") for (int j_ = 0; j_ < 4; ++j_) {                              \
      int drow_ = dq * 4 + j_;                                                      \
      unsigned int hv_ = cvtpk(XR[0][j_], XR[1][j_]);                               \
      *(unsigned int*)(&xt[BUF][drow_ * 64 + ((ng * 2) ^ (swz8(drow_) << 3))]) = hv_; \
    }                                                                               \
  } while (0)

#define PROJ_COMPUTE(CUR)                                                           \
  do {                                                                              \
    _Pragma("unroll") for (int ks2 = 0; ks2 < 2; ++ks2) {                           \
      const int col0 = ks2 * 32 + l4 * 8;                                           \
      bf16x8 a_[2], bb_[4];                                                         \
      _Pragma("unroll") for (int mt_ = 0; mt_ < 2; ++mt_) {                         \
        int row_ = wkk + mt_ * 16 + l15;                                            \
        a_[mt_] = *(const bf16x8*)(&lw[CUR][row_ * 64 + (col0 ^ (swz8(row_) << 3))]); \
      }                                                                             \
      _Pragma("unroll") for (int nt_ = 0; nt_ < 4; ++nt_) {                         \
        int row_ = wdd + nt_ * 16 + l15;                                            \
        bb_[nt_] = *(const bf16x8*)(&xt[CUR][row_ * 64 + (col0 ^ (swz8(row_) << 3))]); \
      }                                                                             \
      _Pragma("unroll") for (int mt_ = 0; mt_ < 2; ++mt_)                           \
        _Pragma("unroll") for (int nt_ = 0; nt_ < 4; ++nt_)                         \
          acc[mt_][nt_] = __builtin_amdgcn_mfma_f32_16x16x32_bf16(a_[mt_], bb_[nt_], \
                                                                  acc[mt_][nt_], 0, 0, 0); \
    }                                                                               \
  } while (0)

  // ---- prologue ----
  PROJ_XISSUE(xA, n0);                                   // X(0): +2
  PROJ_WISSUE(0, n0);                                    // W(0): +2
  asm volatile("s_waitcnt vmcnt(2)" ::: "memory");       // X(0) done
  PROJ_XCVT(xA, 0);
  PROJ_XISSUE(xB, n0 + 64);                              // X(1): +2
  asm volatile("s_waitcnt vmcnt(2)" ::: "memory");       // W(0) done, X(1) flies
  __syncthreads();

  // ---- main loop: iters 0..13 as 7 even/odd pairs (XCVT-early schedule) ----
  for (int itp = 0; itp < 7; ++itp) {
    const int it0 = itp * 2;
    // even iter (cur=0): entry outstanding = X(it+1):2
    PROJ_WISSUE(1, n0 + (it0 + 1) * 64);                 // W(it+1): +2 -> 4
    PROJ_XISSUE(xA, n0 + (it0 + 2) * 64);                // X(it+2): +2 -> 6
    asm volatile("s_waitcnt vmcnt(4)" ::: "memory");     // X(it+1) done (instant)
    PROJ_XCVT(xB, 1);                                    // fill xt[1] for next iter
    PROJ_COMPUTE(0);
    asm volatile("s_waitcnt vmcnt(2)" ::: "memory");     // W(it+1) done (covered)
    __syncthreads();
    // odd iter (cur=1)
    PROJ_WISSUE(0, n0 + (it0 + 2) * 64);
    PROJ_XISSUE(xB, n0 + (it0 + 3) * 64);
    asm volatile("s_waitcnt vmcnt(4)" ::: "memory");
    PROJ_XCVT(xA, 0);
    PROJ_COMPUTE(1);
    asm volatile("s_waitcnt vmcnt(2)" ::: "memory");
    __syncthreads();
  }
  // ---- it=14 (cur=0): entry outstanding = X(15):2 ----
  PROJ_WISSUE(1, n0 + 15 * 64);                          // W(15): +2 -> 4
  asm volatile("s_waitcnt vmcnt(2)" ::: "memory");       // X(15) done
  PROJ_XCVT(xB, 1);
  PROJ_COMPUTE(0);
  asm volatile("s_waitcnt vmcnt(0)" ::: "memory");       // W(15) done
  __syncthreads();
  // ---- it=15 (cur=1) ----
  PROJ_COMPUTE(1);

#undef PROJ_WISSUE
#undef PROJ_XISSUE
#undef PROJ_XCVT
#undef PROJ_COMPUTE

  // ---- write bf16 partials ----
#pragma unroll
  for (int mt = 0; mt < 2; ++mt)
#pragma unroll
    for (int nt = 0; nt < 4; ++nt)
#pragma unroll
      for (int r = 0; r < 4; ++r) {
        int kk = wkk + mt * 16 + l4 * 4 + r;
        int dd = wdd + nt * 16 + l15;
        outp[kk * D_HEAD + dd] = f2bf(acc[mt][nt][r]);
      }
}

// ---------------------------------------------------------------------------
// Stage 1b: reduce 4 bf16 partials + bias. grid 256 (8 sub-blocks per b).
// ---------------------------------------------------------------------------
__global__ __launch_bounds__(256) void reduce_bias_kernel(
    const short* __restrict__ pws, const float* __restrict__ Eb,
    const float* __restrict__ Fb, short* __restrict__ kp, short* __restrict__ vpt) {
  const int q = blockIdx.x & 7;
  const int b = blockIdx.x >> 3;
  const int t = threadIdx.x;
  __shared__ short tile[64 * 128];  // 16KB
  if (q < 4) {
    const short* __restrict__ base = pws + ((size_t)b * 2) * 4 * 32768;
    const int off = q * 8192;
    for (int i = t; i < 8192; i += 256) {
      int ii = off + i;
      int k = ii >> 7;
      float v = bf2f(base[ii]) + bf2f(base[ii + 32768]) + bf2f(base[ii + 65536]) +
                bf2f(base[ii + 98304]) + Eb[k];
      kp[(size_t)b * 32768 + ii] = f2bf(v);
    }
  } else {
    const int kq = q - 4;
    const short* __restrict__ base =
        pws + (((size_t)b * 2 + 1) * 4) * 32768 + kq * 64 * D_HEAD;
    for (int i = t; i < 8192; i += 256) {
      int kl = i >> 7, d = i & 127;
      float v = bf2f(base[i]) + bf2f(base[i + 32768]) + bf2f(base[i + 65536]) +
                bf2f(base[i + 98304]) + Fb[kq * 64 + kl];
      tile[kl * 128 + (d ^ ((kl & 15) << 3))] = f2bf(v);
    }
    __syncthreads();
    for (int i = t; i < 8192; i += 256) {
      int d = i >> 6, kl = i & 63;
      vpt[(size_t)b * 32768 + d * 256 + kq * 64 + kl] = tile[kl * 128 + (d ^ ((kl & 15) << 3))];
    }
  }
}

// ---------------------------------------------------------------------------
// Stage 2: attention v4 + setprio (at HBM floor). grid 256, 1024 thr,
// __launch_bounds__(1024,4), 160KB LDS, zero mid-loop barriers.
// ---------------------------------------------------------------------------
__global__ __launch_bounds__(1024, 4) void attn_kernel(
    const float* __restrict__ Q, const short* __restrict__ kp,
    const short* __restrict__ vpt, float* __restrict__ out) {
  const int bid = blockIdx.x;
  const int wk = (bid & 7) * 32 + (bid >> 3);  // XCD-chunked: 4 b's per XCD
  const int b = wk >> 3;
  const int slice = wk & 7;
  const int t = threadIdx.x;
  const int lane = t & 63;
  const int w = t >> 6;  // 0..15
  const int l15 = lane & 15, l4 = lane >> 4;

  __shared__ __align__(16) short lbuf[81920];
  short* lkp = lbuf;
  short* lvpt = lbuf + 32768;
  short* lpw = lbuf + 65536 + w * 1024;  // 2KB/wave

  const short* __restrict__ kpb = kp + (size_t)b * 32768;
  const short* __restrict__ vptb = vpt + (size_t)b * 32768;

#pragma unroll
  for (int i = 0; i < 4; ++i) {
    int g = t + i * 1024;
    int row = g >> 4, c = g & 15;
    __builtin_amdgcn_global_load_lds(
        (const __attribute__((address_space(1))) void*)(kpb + (size_t)row * 128 +
                                                        ((c ^ (row & 7)) << 3)),
        (__attribute__((address_space(3))) void*)(&lkp[g * 8]), 16, 0, 0);
  }
#pragma unroll
  for (int i = 0; i < 4; ++i) {
    int g = t + i * 1024;
    int row = g >> 5, c = g & 31;
    __builtin_amdgcn_global_load_lds(
        (const __attribute__((address_space(1))) void*)(vptb + (size_t)row * 256 +
                                                        ((c ^ (row & 7)) << 3)),
        (__attribute__((address_space(3))) void*)(&lvpt[g * 8]), 16, 0, 0);
  }

  const float scale = 0.08838834764831845f;  // 1/sqrt(128)
  f32x4 qraw[8];
  {
    const float* qr = Q + ((size_t)b * N_SEQ + slice * 512 + w * 16 + l15) * D_HEAD;
#pragma unroll
    for (int ks = 0; ks < 4; ++ks) {
      qraw[2 * ks] = *(const f32x4*)(qr + ks * 32 + l4 * 8);
      qraw[2 * ks + 1] = *(const f32x4*)(qr + ks * 32 + l4 * 8 + 4);
    }
  }
  asm volatile("s_waitcnt vmcnt(0)" ::: "memory");
  __syncthreads();

#pragma unroll
  for (int rd = 0; rd < 2; ++rd) {
    const int rowBase = slice * 512 + rd * 256 + w * 16;

    bf16x8 qf[4];
#pragma unroll
    for (int ks = 0; ks < 4; ++ks) {
      union { unsigned int u[4]; bf16x8 v; } cv;
      cv.u[0] = cvtpk(qraw[2 * ks][0] * scale, qraw[2 * ks][1] * scale);
      cv.u[1] = cvtpk(qraw[2 * ks][2] * scale, qraw[2 * ks][3] * scale);
      cv.u[2] = cvtpk(qraw[2 * ks + 1][0] * scale, qraw[2 * ks + 1][1] * scale);
      cv.u[3] = cvtpk(qraw[2 * ks + 1][2] * scale, qraw[2 * ks + 1][3] * scale);
      qf[ks] = cv.v;
    }

    f32x4 accs[16];
#pragma unroll
    for (int i = 0; i < 16; ++i) accs[i] = (f32x4){0.f, 0.f, 0.f, 0.f};
    __builtin_amdgcn_s_setprio(1);
#pragma unroll
    for (int ks = 0; ks < 4; ++ks) {
#pragma unroll
      for (int nt = 0; nt < 16; ++nt) {
        bf16x8 af = *(const bf16x8*)(&lkp[(nt * 16 + l15) * 128 +
                                          (((ks * 4 + l4) ^ (l15 & 7)) << 3)]);
        accs[nt] = __builtin_amdgcn_mfma_f32_16x16x32_bf16(af, qf[ks], accs[nt], 0, 0, 0);
      }
    }
    __builtin_amdgcn_s_setprio(0);

    float m = -1e30f;
#pragma unroll
    for (int nt = 0; nt < 16; ++nt)
#pragma unroll
      for (int r = 0; r < 4; ++r) m = fmaxf(m, accs[nt][r]);
    m = fmaxf(m, __shfl_xor(m, 16));
    m = fmaxf(m, __shfl_xor(m, 32));
    float s = 0.f;
#pragma unroll
    for (int nt = 0; nt < 16; ++nt)
#pragma unroll
      for (int r = 0; r < 4; ++r) {
        float e = __expf(accs[nt][r] - m);
        accs[nt][r] = e;
        s += e;
      }
    s += __shfl_xor(s, 16);
    s += __shfl_xor(s, 32);
    float inv = 1.0f / s;

    f32x4 acco[8];
#pragma unroll
    for (int i = 0; i < 8; ++i) acco[i] = (f32x4){0.f, 0.f, 0.f, 0.f};
#pragma unroll
    for (int qq = 0; qq < 4; ++qq) {
#pragma unroll
      for (int ntl = 0; ntl < 4; ++ntl) {
        int nt = qq * 4 + ntl;
        int cw = 2 * ntl + (l4 >> 1);
        unsigned int p0 = cvtpk(accs[nt][0] * inv, accs[nt][1] * inv);
        unsigned int p1 = cvtpk(accs[nt][2] * inv, accs[nt][3] * inv);
        *(u32x2*)((char*)lpw + l15 * 128 + ((cw ^ (l15 & 7)) << 4) + (l4 & 1) * 8) =
            (u32x2){p0, p1};
      }
      if (rd == 0 && qq == 3) {
        const float* qr = Q + ((size_t)b * N_SEQ + slice * 512 + 256 + w * 16 + l15) * D_HEAD;
#pragma unroll
        for (int ks = 0; ks < 4; ++ks) {
          qraw[2 * ks] = *(const f32x4*)(qr + ks * 32 + l4 * 8);
          qraw[2 * ks + 1] = *(const f32x4*)(qr + ks * 32 + l4 * 8 + 4);
        }
      }
      __builtin_amdgcn_s_setprio(1);
#pragma unroll
      for (int ksl = 0; ksl < 2; ++ksl) {
        bf16x8 pa = *(const bf16x8*)((char*)lpw + l15 * 128 +
                                     (((4 * ksl + l4) ^ (l15 & 7)) << 4));
        int ksa = qq * 2 + ksl;
#pragma unroll
        for (int ntv = 0; ntv < 8; ++ntv) {
          bf16x8 av = *(const bf16x8*)(&lvpt[(ntv * 16 + l15) * 256 +
                                             (((ksa * 4 + l4) ^ (l15 & 7)) << 3)]);
          acco[ntv] = __builtin_amdgcn_mfma_f32_16x16x32_bf16(av, pa, acco[ntv], 0, 0, 0);
        }
      }
      __builtin_amdgcn_s_setprio(0);
    }

    float* ob = out + ((size_t)b * N_SEQ + rowBase) * D_HEAD;
#pragma unroll
    for (int ntv = 0; ntv < 8; ++ntv)
      *(f32x4*)(ob + (size_t)l15 * D_HEAD + ntv * 16 + l4 * 4) = acco[ntv];
  }
}

// ---------------------------------------------------------------------------
extern "C" void kernel_launch(void* const* d_in, const int* in_sizes, int n_in,
                              void* d_out, int out_size, void* d_ws, size_t ws_size,
                              hipStream_t stream) {
  const float* Q  = (const float*)d_in[0];
  const float* K  = (const float*)d_in[1];
  const float* V  = (const float*)d_in[2];
  const float* EW = (const float*)d_in[3];
  const float* Eb = (const float*)d_in[4];
  const float* FW = (const float*)d_in[5];
  const float* Fb = (const float*)d_in[6];
  float* out = (float*)d_out;

  // d_out scratch (dead before attn writes): [0,4MB) wbf; [8MB,24.8MB) pws bf16
  short* wbf = (short*)d_out;
  short* pws = (short*)((char*)d_out + 8 * 1024 * 1024);
  short* kpb = (short*)d_ws;
  short* vpt = (short*)((char*)d_ws + (size_t)32 * KP_DIM * D_HEAD * 2);

  conv_w_kernel<<<dim3(2048), dim3(256), 0, stream>>>(EW, FW, wbf);
  proj_partial_kernel<<<dim3(256), dim3(1024), 0, stream>>>(K, V, wbf, pws);
  reduce_bias_kernel<<<dim3(256), dim3(256), 0, stream>>>(pws, Eb, Fb, kpb, vpt);
  attn_kernel<<<dim3(256), dim3(1024), 0, stream>>>(Q, kpb, vpt, out);
}